// Round 1
// baseline (267.593 us; speedup 1.0000x reference)
//
#include <hip/hip_runtime.h>
#include <hip/hip_bf16.h>

typedef unsigned short u16;
typedef unsigned int u32;
typedef __attribute__((ext_vector_type(8))) short short8;   // 8 bf16 for MFMA frags
typedef __attribute__((ext_vector_type(8))) u16 ushort8;
typedef __attribute__((ext_vector_type(4))) float f32x4;

// ---------- constants ----------
#define BB 2048
#define SS 8
#define DNUM 8
#define LL 50
#define EDIM 16
#define FDIM 512
#define HID1 256
#define HID2 128
#define NEXP 8
#define NTASK 4
#define EOUT 8
#define KDNN 1216          // 1160 padded to 64-multiple
#define ROWS (BB*LL)       // 102400

// ---------- helpers ----------
__device__ inline u16 f2bf(float x) {
    u32 u = __builtin_bit_cast(u32, x);
    u32 r = (u + 0x7FFFu + ((u >> 16) & 1u)) >> 16;   // RNE
    return (u16)r;
}
__device__ inline float bf2f(u16 b) {
    u32 u = ((u32)b) << 16;
    return __builtin_bit_cast(float, u);
}
__device__ inline void load16_lds(const void* g, void* l) {
    __builtin_amdgcn_global_load_lds(
        (const __attribute__((address_space(1))) u32*)g,
        (__attribute__((address_space(3))) u32*)l, 16, 0, 0);
}
__device__ inline float wave_sum(float v) {
    #pragma unroll
    for (int off = 32; off > 0; off >>= 1) v += __shfl_xor(v, off, 64);
    return v;
}
__device__ inline float wave_max(float v) {
    #pragma unroll
    for (int off = 32; off > 0; off >>= 1) v = fmaxf(v, __shfl_xor(v, off, 64));
    return v;
}
__device__ inline void cvt8(const float4& a, const float4& b, ushort8& o) {
    o[0]=f2bf(a.x); o[1]=f2bf(a.y); o[2]=f2bf(a.z); o[3]=f2bf(a.w);
    o[4]=f2bf(b.x); o[5]=f2bf(b.y); o[6]=f2bf(b.z); o[7]=f2bf(b.w);
}

// ---------- K0: weight prep (combine + transpose + bf16) ----------
// WHP_T [128n][1024k]: k<512 -> Wh = W1b-W1c ; k>=512 -> Wp = W1d
// WQ_T  [128n][512k] : Wq = W1a+W1c
// W1D_T [256n][1216k]: dnn_w1^T zero-padded ; W2D_T [128n][256k]: dnn_w2^T
__global__ __launch_bounds__(256) void prep_weights(
    const float* __restrict__ w1, const float* __restrict__ dw1,
    const float* __restrict__ dw2,
    u16* __restrict__ WHP_T, u16* __restrict__ WQ_T,
    u16* __restrict__ W1D_T, u16* __restrict__ W2D_T)
{
    int idx = blockIdx.x * 256 + threadIdx.x;
    if (idx < 131072) {
        int n = idx >> 10, k = idx & 1023;
        float v;
        if (k < 512) v = w1[(512 + k) * 128 + n] - w1[(1024 + k) * 128 + n];
        else         v = w1[(1024 + k) * 128 + n];   // 1536 + (k-512)
        WHP_T[n * 1024 + k] = f2bf(v);
    } else if (idx < 196608) {
        int i = idx - 131072;
        int n = i >> 9, k = i & 511;
        WQ_T[n * 512 + k] = f2bf(w1[k * 128 + n] + w1[(1024 + k) * 128 + n]);
    } else if (idx < 507904) {
        int i = idx - 196608;
        int n = i / KDNN, k = i - n * KDNN;
        W1D_T[i] = (k < 1160) ? f2bf(dw1[k * HID1 + n]) : (u16)0;
    } else if (idx < 540672) {
        int i = idx - 507904;
        int n = i >> 8, k = i & 255;
        W2D_T[i] = f2bf(dw2[k * HID2 + n]);
    }
}

// ---------- K1a: build A rows (single-GEMM path): [bf16(h) | bf16(q*h)] ----------
__global__ __launch_bounds__(64) void build_A_hp(
    const int* __restrict__ hist_ids, const int* __restrict__ feedid,
    const float* __restrict__ feed_table, u16* __restrict__ A)
{
    int row = blockIdx.x;
    int b = row / LL;
    int hid = hist_ids[row];
    int fid = feedid[b];
    int k0 = threadIdx.x * 8;
    const float4* hp = (const float4*)&feed_table[(size_t)hid * FDIM + k0];
    const float4* qp = (const float4*)&feed_table[(size_t)fid * FDIM + k0];
    float4 h0 = hp[0], h1 = hp[1];
    float4 q0 = qp[0], q1 = qp[1];
    ushort8 hv, pv;
    cvt8(h0, h1, hv);
    float4 p0 = make_float4(h0.x*q0.x, h0.y*q0.y, h0.z*q0.z, h0.w*q0.w);
    float4 p1 = make_float4(h1.x*q1.x, h1.y*q1.y, h1.z*q1.z, h1.w*q1.w);
    cvt8(p0, p1, pv);
    *(ushort8*)&A[(size_t)row * 1024 + k0] = hv;
    *(ushort8*)&A[(size_t)row * 1024 + 512 + k0] = pv;
}

// ---------- K1a': two-pass variants ----------
__global__ __launch_bounds__(64) void build_A_h(
    const int* __restrict__ hist_ids, const float* __restrict__ feed_table,
    u16* __restrict__ A)
{
    int row = blockIdx.x;
    int hid = hist_ids[row];
    int k0 = threadIdx.x * 8;
    const float4* hp = (const float4*)&feed_table[(size_t)hid * FDIM + k0];
    float4 h0 = hp[0], h1 = hp[1];
    ushort8 hv; cvt8(h0, h1, hv);
    *(ushort8*)&A[(size_t)row * 512 + k0] = hv;
}
__global__ __launch_bounds__(64) void mulq_A(
    const int* __restrict__ feedid, const float* __restrict__ feed_table,
    u16* __restrict__ A)
{
    int row = blockIdx.x;
    int b = row / LL;
    int fid = feedid[b];
    int k0 = threadIdx.x * 8;
    ushort8 hv = *(ushort8*)&A[(size_t)row * 512 + k0];
    const float4* qp = (const float4*)&feed_table[(size_t)fid * FDIM + k0];
    float4 q0 = qp[0], q1 = qp[1];
    ushort8 pv;
    pv[0]=f2bf(bf2f(hv[0])*q0.x); pv[1]=f2bf(bf2f(hv[1])*q0.y);
    pv[2]=f2bf(bf2f(hv[2])*q0.z); pv[3]=f2bf(bf2f(hv[3])*q0.w);
    pv[4]=f2bf(bf2f(hv[4])*q1.x); pv[5]=f2bf(bf2f(hv[5])*q1.y);
    pv[6]=f2bf(bf2f(hv[6])*q1.z); pv[7]=f2bf(bf2f(hv[7])*q1.w);
    *(ushort8*)&A[(size_t)row * 512 + k0] = pv;
}

// ---------- K1b: per-b gather: sparse emb + dense + feed -> dnn_in (bf16), A_q ----------
__global__ __launch_bounds__(256) void gather_b(
    const int* __restrict__ sparse_ids, const float* __restrict__ dense,
    const int* __restrict__ feedid, const float* __restrict__ emb_tables,
    const float* __restrict__ feed_table,
    u16* __restrict__ dnn_in, u16* __restrict__ A_q)
{
    int b = blockIdx.x, t = threadIdx.x;
    u16* drow = dnn_in + (size_t)b * KDNN;
    if (t < 128) {
        int s = t >> 4, e = t & 15;
        int id = sparse_ids[b * SS + s];
        float v = emb_tables[(size_t)s * 1600000 + (size_t)id * EDIM + e];
        drow[t] = f2bf(v);
    } else if (t < 136) {
        drow[t] = f2bf(dense[b * DNUM + (t - 128)]);
    } else if (t < 192) {
        drow[1160 + (t - 136)] = 0;   // K padding
    }
    int fid = feedid[b];
    float2 f = *(const float2*)&feed_table[(size_t)fid * FDIM + t * 2];
    u16 u0 = f2bf(f.x), u1 = f2bf(f.y);
    drow[136 + t * 2] = u0;
    drow[136 + t * 2 + 1] = u1;
    A_q[(size_t)b * FDIM + t * 2] = u0;
    A_q[(size_t)b * FDIM + t * 2 + 1] = u1;
}

// ---------- K2: bf16 MFMA GEMM, C = A[M,K] @ BT[N,K]^T (m97 structure) ----------
template<bool RELU, bool OUT_BF16, bool ACC>
__global__ __launch_bounds__(256) void gemm_bt(
    const u16* __restrict__ A, int lda,
    const u16* __restrict__ BT, int ldb,
    const float* __restrict__ bias,
    void* __restrict__ Cv, int M, int N, int K)
{
    __shared__ u16 As[128 * 64];
    __shared__ u16 Bs[128 * 64];
    int m0 = blockIdx.x * 128, n0 = blockIdx.y * 128;
    int tid = threadIdx.x, wave = tid >> 6, lane = tid & 63;
    int lrow = lane >> 3, lk = (lane & 7) * 8;
    f32x4 acc[4][4];
    f32x4 zz = {0.f, 0.f, 0.f, 0.f};
    #pragma unroll
    for (int i = 0; i < 4; i++)
        #pragma unroll
        for (int j = 0; j < 4; j++) acc[i][j] = zz;
    int wm = (wave >> 1) * 64, wn = (wave & 1) * 64;

    for (int kt = 0; kt < K; kt += 64) {
        #pragma unroll
        for (int j = 0; j < 4; ++j) {
            int c = wave * 4 + j;          // chunk: 8 rows x 64 k (1 KiB)
            int row = c * 8 + lrow;
            load16_lds(A  + (size_t)(m0 + row) * lda + kt + lk, &As[c * 512]);
            load16_lds(BT + (size_t)(n0 + row) * ldb + kt + lk, &Bs[c * 512]);
        }
        __syncthreads();
        #pragma unroll
        for (int ks = 0; ks < 2; ++ks) {
            int kk = ks * 32 + (lane >> 4) * 8;
            short8 af[4], bf[4];
            #pragma unroll
            for (int i = 0; i < 4; i++)
                af[i] = *(const short8*)&As[(wm + i * 16 + (lane & 15)) * 64 + kk];
            #pragma unroll
            for (int j = 0; j < 4; j++)
                bf[j] = *(const short8*)&Bs[(wn + j * 16 + (lane & 15)) * 64 + kk];
            #pragma unroll
            for (int i = 0; i < 4; i++)
                #pragma unroll
                for (int j = 0; j < 4; j++)
                    acc[i][j] = __builtin_amdgcn_mfma_f32_16x16x32_bf16(
                        af[i], bf[j], acc[i][j], 0, 0, 0);
        }
        __syncthreads();
    }
    // epilogue: D row=(lane>>4)*4+r, col=lane&15 within each 16x16 tile
    #pragma unroll
    for (int i = 0; i < 4; i++) {
        #pragma unroll
        for (int j = 0; j < 4; j++) {
            #pragma unroll
            for (int r = 0; r < 4; r++) {
                int row = m0 + wm + i * 16 + (lane >> 4) * 4 + r;
                int col = n0 + wn + j * 16 + (lane & 15);
                float v = acc[i][j][r];
                if (bias) v += bias[col];
                size_t off = (size_t)row * N + col;
                if (ACC) v += ((const float*)Cv)[off];
                if (RELU) v = fmaxf(v, 0.f);
                if (OUT_BF16) ((u16*)Cv)[off] = f2bf(v);
                else ((float*)Cv)[off] = v;
            }
        }
    }
}

// ---------- K3: fused scores + softmax + user_interest ----------
__global__ __launch_bounds__(256) void scores_ui(
    const float* __restrict__ mlp,       // [ROWS,128] = h·Wh + (q⊙h)·Wp
    const float* __restrict__ qw,        // [B,128]    = q·Wq
    const float* __restrict__ b1, const float* __restrict__ w2v,
    const float* __restrict__ b2p,
    const u16* __restrict__ Ah,          // nullable; stride 1024, h at [0:512]
    const int* __restrict__ hist_ids, const float* __restrict__ feed_table,
    u16* __restrict__ dnn_in)
{
    int b = blockIdx.x, t = threadIdx.x;
    int wave = t >> 6, lane = t & 63;
    __shared__ float sc[52];
    float qb0 = qw[b * 128 + lane] + b1[lane];
    float qb1 = qw[b * 128 + 64 + lane] + b1[64 + lane];
    float w20 = w2v[lane], w21 = w2v[64 + lane];
    float b2 = b2p[0];
    for (int l = wave; l < LL; l += 4) {
        const float* mr = mlp + (size_t)(b * LL + l) * 128;
        float v0 = mr[lane] + qb0, v1 = mr[64 + lane] + qb1;
        float s = fmaxf(v0, 0.f) * w20 + fmaxf(v1, 0.f) * w21;
        s = wave_sum(s);
        if (lane == 0) sc[l] = s + b2;
    }
    __syncthreads();
    if (wave == 0) {
        float x = (lane < LL) ? sc[lane] : -1e30f;
        float mx = wave_max(x);
        float e = (lane < LL) ? __expf(x - mx) : 0.f;
        float s = wave_sum(e);
        if (lane < LL) sc[lane] = e / s;
    }
    __syncthreads();
    int d = t * 2;
    float a0 = 0.f, a1 = 0.f;
    if (Ah) {
        const u16* base = Ah + (size_t)b * LL * 1024 + d;
        for (int l = 0; l < LL; ++l) {
            u32 v = *(const u32*)(base + (size_t)l * 1024);
            float al = sc[l];
            a0 += al * bf2f((u16)(v & 0xffff));
            a1 += al * bf2f((u16)(v >> 16));
        }
    } else {
        const int* hid = hist_ids + b * LL;
        for (int l = 0; l < LL; ++l) {
            float2 hv = *(const float2*)&feed_table[(size_t)hid[l] * FDIM + d];
            float al = sc[l];
            a0 += al * hv.x;
            a1 += al * hv.y;
        }
    }
    dnn_in[(size_t)b * KDNN + 648 + d] = f2bf(a0);
    dnn_in[(size_t)b * KDNN + 648 + d + 1] = f2bf(a1);
}

// ---------- K8: MMOE + task heads (one wave per sample) ----------
__global__ __launch_bounds__(256) void mmoe_head(
    const float* __restrict__ dnn_out, const float* __restrict__ expert_w,
    const float* __restrict__ gate_w, const float* __restrict__ out_w,
    const float* __restrict__ out_b, float* __restrict__ out)
{
    int wave = threadIdx.x >> 6, lane = threadIdx.x & 63;
    int b = blockIdx.x * 4 + wave;
    __shared__ float ds[4][128];
    __shared__ float eo[4][64];
    __shared__ float gt[4][32];
    ds[wave][lane] = dnn_out[b * 128 + lane];
    ds[wave][lane + 64] = dnn_out[b * 128 + 64 + lane];
    __syncthreads();
    int e = lane >> 3, o = lane & 7;
    float acc = 0.f;
    for (int k = 0; k < 128; ++k)
        acc += ds[wave][k] * expert_w[(e * 128 + k) * 8 + o];
    eo[wave][lane] = acc;
    if (lane < 32) {
        int tt = lane >> 3, ee = lane & 7;
        float g = 0.f;
        for (int k = 0; k < 128; ++k)
            g += ds[wave][k] * gate_w[(tt * 128 + k) * 8 + ee];
        float m = g;
        #pragma unroll
        for (int off = 4; off; off >>= 1) m = fmaxf(m, __shfl_xor(m, off, 8));
        float ex = __expf(g - m);
        float s = ex;
        #pragma unroll
        for (int off = 4; off; off >>= 1) s += __shfl_xor(s, off, 8);
        gt[wave][lane] = ex / s;
    }
    __syncthreads();
    if (lane < 32) {
        int tt = lane >> 3, o2 = lane & 7;
        float to = 0.f;
        #pragma unroll
        for (int ee = 0; ee < 8; ++ee)
            to += gt[wave][tt * 8 + ee] * eo[wave][ee * 8 + o2];
        float pl = to * out_w[tt * 8 + o2];
        #pragma unroll
        for (int off = 4; off; off >>= 1) pl += __shfl_xor(pl, off, 8);
        if (o2 == 0) {
            float logit = pl + out_b[tt];
            out[b * 4 + tt] = 1.f / (1.f + __expf(-logit));
        }
    }
}

// ---------- host ----------
extern "C" void kernel_launch(void* const* d_in, const int* in_sizes, int n_in,
                              void* d_out, int out_size, void* d_ws, size_t ws_size,
                              hipStream_t stream)
{
    const int*   sparse_ids = (const int*)d_in[0];
    const float* dense      = (const float*)d_in[1];
    const int*   feedid     = (const int*)d_in[2];
    const int*   hist_ids   = (const int*)d_in[3];
    const float* emb_tables = (const float*)d_in[4];
    const float* feed_table = (const float*)d_in[5];
    const float* attn_w1    = (const float*)d_in[6];
    const float* attn_b1    = (const float*)d_in[7];
    const float* attn_w2    = (const float*)d_in[8];
    const float* attn_b2    = (const float*)d_in[9];
    const float* dnn_w1     = (const float*)d_in[10];
    const float* dnn_b1     = (const float*)d_in[11];
    const float* dnn_w2     = (const float*)d_in[12];
    const float* dnn_b2     = (const float*)d_in[13];
    const float* expert_w   = (const float*)d_in[14];
    const float* gate_w     = (const float*)d_in[15];
    const float* out_w      = (const float*)d_in[16];
    const float* out_b      = (const float*)d_in[17];
    float* out = (float*)d_out;

    char* ws = (char*)d_ws;
    size_t off = 0;
    auto alloc = [&](size_t bytes) {
        char* p = ws + off;
        off += (bytes + 255) & ~(size_t)255;
        return p;
    };
    u16* WHP_T = (u16*)alloc(131072 * 2);
    u16* WQ_T  = (u16*)alloc(65536 * 2);
    u16* W1D_T = (u16*)alloc((size_t)HID1 * KDNN * 2);
    u16* W2D_T = (u16*)alloc((size_t)HID2 * HID1 * 2);
    u16* AQ    = (u16*)alloc((size_t)BB * FDIM * 2);
    float* QW  = (float*)alloc((size_t)BB * 128 * 4);
    u16* DNNIN = (u16*)alloc((size_t)BB * KDNN * 2);
    u16* Z     = (u16*)alloc((size_t)BB * HID1 * 2);
    float* DOUT= (float*)alloc((size_t)BB * HID2 * 4);
    float* MLP = (float*)alloc((size_t)ROWS * 128 * 4);
    size_t fixed = off;
    bool single = (ws_size >= fixed + (size_t)ROWS * 1024 * 2);
    u16* Abuf = (u16*)alloc(single ? (size_t)ROWS * 1024 * 2
                                   : (size_t)ROWS * 512 * 2);

    prep_weights<<<2112, 256, 0, stream>>>(attn_w1, dnn_w1, dnn_w2,
                                           WHP_T, WQ_T, W1D_T, W2D_T);
    gather_b<<<BB, 256, 0, stream>>>(sparse_ids, dense, feedid, emb_tables,
                                     feed_table, DNNIN, AQ);
    if (single) {
        build_A_hp<<<ROWS, 64, 0, stream>>>(hist_ids, feedid, feed_table, Abuf);
        gemm_bt<false, false, false><<<dim3(ROWS / 128, 1), 256, 0, stream>>>(
            Abuf, 1024, WHP_T, 1024, nullptr, MLP, ROWS, 128, 1024);
    } else {
        build_A_h<<<ROWS, 64, 0, stream>>>(hist_ids, feed_table, Abuf);
        gemm_bt<false, false, false><<<dim3(ROWS / 128, 1), 256, 0, stream>>>(
            Abuf, 512, WHP_T, 1024, nullptr, MLP, ROWS, 128, 512);
        mulq_A<<<ROWS, 64, 0, stream>>>(feedid, feed_table, Abuf);
        gemm_bt<false, false, true><<<dim3(ROWS / 128, 1), 256, 0, stream>>>(
            Abuf, 512, WHP_T + 512, 1024, nullptr, MLP, ROWS, 128, 512);
    }
    gemm_bt<false, false, false><<<dim3(BB / 128, 1), 256, 0, stream>>>(
        AQ, 512, WQ_T, 512, nullptr, QW, BB, 128, 512);
    scores_ui<<<BB, 256, 0, stream>>>(MLP, QW, attn_b1, attn_w2, attn_b2,
                                      single ? Abuf : (const u16*)nullptr,
                                      hist_ids, feed_table, DNNIN);
    gemm_bt<true, true, false><<<dim3(BB / 128, HID1 / 128), 256, 0, stream>>>(
        DNNIN, KDNN, W1D_T, KDNN, dnn_b1, Z, BB, HID1, KDNN);
    gemm_bt<true, false, false><<<dim3(BB / 128, 1), 256, 0, stream>>>(
        Z, HID1, W2D_T, HID1, dnn_b2, DOUT, BB, HID2, HID1);
    mmoe_head<<<BB / 4, 256, 0, stream>>>(DOUT, expert_w, gate_w, out_w,
                                          out_b, out);
}

// Round 2
// 199.645 us; speedup vs baseline: 1.3403x; 1.3403x over previous
//
#include <hip/hip_runtime.h>
#include <hip/hip_bf16.h>

typedef unsigned short u16;
typedef unsigned int u32;
typedef __attribute__((ext_vector_type(8))) short short8;   // 8 bf16 for MFMA frags
typedef __attribute__((ext_vector_type(8))) u16 ushort8;
typedef __attribute__((ext_vector_type(4))) float f32x4;

// ---------- constants ----------
#define BB 2048
#define SS 8
#define DNUM 8
#define LL 50
#define EDIM 16
#define FDIM 512
#define HID1 256
#define HID2 128
#define KDNN 1216          // 1160 padded to 64-multiple
#define ROWS (BB*LL)       // 102400

// ---------- helpers ----------
__device__ inline u16 f2bf(float x) {
    u32 u = __builtin_bit_cast(u32, x);
    u32 r = (u + 0x7FFFu + ((u >> 16) & 1u)) >> 16;   // RNE
    return (u16)r;
}
__device__ inline float bf2f(u16 b) {
    u32 u = ((u32)b) << 16;
    return __builtin_bit_cast(float, u);
}
__device__ inline void load16_lds(const void* g, void* l) {
    __builtin_amdgcn_global_load_lds(
        (const __attribute__((address_space(1))) u32*)g,
        (__attribute__((address_space(3))) u32*)l, 16, 0, 0);
}
__device__ inline float wave_sum(float v) {
    #pragma unroll
    for (int off = 32; off > 0; off >>= 1) v += __shfl_xor(v, off, 64);
    return v;
}
__device__ inline float wave_max(float v) {
    #pragma unroll
    for (int off = 32; off > 0; off >>= 1) v = fmaxf(v, __shfl_xor(v, off, 64));
    return v;
}
__device__ inline void cvt8(const float4& a, const float4& b, ushort8& o) {
    o[0]=f2bf(a.x); o[1]=f2bf(a.y); o[2]=f2bf(a.z); o[3]=f2bf(a.w);
    o[4]=f2bf(b.x); o[5]=f2bf(b.y); o[6]=f2bf(b.z); o[7]=f2bf(b.w);
}

// ---------- K0: weight prep (combine + transpose + bf16) ----------
__global__ __launch_bounds__(256) void prep_weights(
    const float* __restrict__ w1, const float* __restrict__ dw1,
    const float* __restrict__ dw2,
    u16* __restrict__ WHP_T, u16* __restrict__ WQ_T,
    u16* __restrict__ W1D_T, u16* __restrict__ W2D_T)
{
    int idx = blockIdx.x * 256 + threadIdx.x;
    if (idx < 131072) {
        int n = idx >> 10, k = idx & 1023;
        float v;
        if (k < 512) v = w1[(512 + k) * 128 + n] - w1[(1024 + k) * 128 + n];
        else         v = w1[(1024 + k) * 128 + n];   // 1536 + (k-512)
        WHP_T[n * 1024 + k] = f2bf(v);
    } else if (idx < 196608) {
        int i = idx - 131072;
        int n = i >> 9, k = i & 511;
        WQ_T[n * 512 + k] = f2bf(w1[k * 128 + n] + w1[(1024 + k) * 128 + n]);
    } else if (idx < 507904) {
        int i = idx - 196608;
        int n = i / KDNN, k = i - n * KDNN;
        W1D_T[i] = (k < 1160) ? f2bf(dw1[k * HID1 + n]) : (u16)0;
    } else if (idx < 540672) {
        int i = idx - 507904;
        int n = i >> 8, k = i & 255;
        W2D_T[i] = f2bf(dw2[k * HID2 + n]);
    }
}

// ---------- K1: per-b gather: sparse emb + dense + feed -> dnn_in (bf16), A_q ----------
__global__ __launch_bounds__(256) void gather_b(
    const int* __restrict__ sparse_ids, const float* __restrict__ dense,
    const int* __restrict__ feedid, const float* __restrict__ emb_tables,
    const float* __restrict__ feed_table,
    u16* __restrict__ dnn_in, u16* __restrict__ A_q)
{
    int b = blockIdx.x, t = threadIdx.x;
    u16* drow = dnn_in + (size_t)b * KDNN;
    if (t < 128) {
        int s = t >> 4, e = t & 15;
        int id = sparse_ids[b * SS + s];
        float v = emb_tables[(size_t)s * 1600000 + (size_t)id * EDIM + e];
        drow[t] = f2bf(v);
    } else if (t < 136) {
        drow[t] = f2bf(dense[b * DNUM + (t - 128)]);
    } else if (t < 192) {
        drow[1160 + (t - 136)] = 0;   // K padding
    }
    int fid = feedid[b];
    float2 f = *(const float2*)&feed_table[(size_t)fid * FDIM + t * 2];
    u16 u0 = f2bf(f.x), u1 = f2bf(f.y);
    drow[136 + t * 2] = u0;
    drow[136 + t * 2 + 1] = u1;
    A_q[(size_t)b * FDIM + t * 2] = u0;
    A_q[(size_t)b * FDIM + t * 2 + 1] = u1;
}

// ---------- K2: generic bf16 MFMA GEMM (qw + DNN layers) ----------
template<bool RELU, bool OUT_BF16>
__global__ __launch_bounds__(256) void gemm_bt(
    const u16* __restrict__ A, int lda,
    const u16* __restrict__ BT, int ldb,
    const float* __restrict__ bias,
    void* __restrict__ Cv, int M, int N, int K)
{
    __shared__ u16 As[128 * 64];
    __shared__ u16 Bs[128 * 64];
    int m0 = blockIdx.x * 128, n0 = blockIdx.y * 128;
    int tid = threadIdx.x, wave = tid >> 6, lane = tid & 63;
    int lrow = lane >> 3, lk = (lane & 7) * 8;
    f32x4 acc[4][4];
    f32x4 zz = {0.f, 0.f, 0.f, 0.f};
    #pragma unroll
    for (int i = 0; i < 4; i++)
        #pragma unroll
        for (int j = 0; j < 4; j++) acc[i][j] = zz;
    int wm = (wave >> 1) * 64, wn = (wave & 1) * 64;

    for (int kt = 0; kt < K; kt += 64) {
        #pragma unroll
        for (int j = 0; j < 4; ++j) {
            int c = wave * 4 + j;
            int row = c * 8 + lrow;
            load16_lds(A  + (size_t)(m0 + row) * lda + kt + lk, &As[c * 512]);
            load16_lds(BT + (size_t)(n0 + row) * ldb + kt + lk, &Bs[c * 512]);
        }
        __syncthreads();
        #pragma unroll
        for (int ks = 0; ks < 2; ++ks) {
            int kk = ks * 32 + (lane >> 4) * 8;
            short8 af[4], bf[4];
            #pragma unroll
            for (int i = 0; i < 4; i++)
                af[i] = *(const short8*)&As[(wm + i * 16 + (lane & 15)) * 64 + kk];
            #pragma unroll
            for (int j = 0; j < 4; j++)
                bf[j] = *(const short8*)&Bs[(wn + j * 16 + (lane & 15)) * 64 + kk];
            #pragma unroll
            for (int i = 0; i < 4; i++)
                #pragma unroll
                for (int j = 0; j < 4; j++)
                    acc[i][j] = __builtin_amdgcn_mfma_f32_16x16x32_bf16(
                        af[i], bf[j], acc[i][j], 0, 0, 0);
        }
        __syncthreads();
    }
    #pragma unroll
    for (int i = 0; i < 4; i++) {
        #pragma unroll
        for (int j = 0; j < 4; j++) {
            #pragma unroll
            for (int r = 0; r < 4; r++) {
                int row = m0 + wm + i * 16 + (lane >> 4) * 4 + r;
                int col = n0 + wn + j * 16 + (lane & 15);
                float v = acc[i][j][r];
                if (bias) v += bias[col];
                if (RELU) v = fmaxf(v, 0.f);
                size_t off = (size_t)row * N + col;
                if (OUT_BF16) ((u16*)Cv)[off] = f2bf(v);
                else ((float*)Cv)[off] = v;
            }
        }
    }
}

// ---------- K3: fused DIN GEMM ----------
// Gathers h rows from feed_table (f32), builds bf16 [h] and [q*h] tiles in
// LDS via registers, accumulates C = h@Wh + (q*h)@Wp with dual MFMA streams,
// side-writes Ah (bf16 h rows, needed by user-interest), and computes
// scores[row] = sum_col relu(C+qw+b1)*w2 + b2 in the epilogue.
__global__ __launch_bounds__(256) void din_gemm(
    const int* __restrict__ hist_ids, const int* __restrict__ feedid,
    const float* __restrict__ feed_table,
    const u16* __restrict__ WHP_T,
    const float* __restrict__ qw, const float* __restrict__ b1,
    const float* __restrict__ w2v, const float* __restrict__ b2p,
    u16* __restrict__ Ah, float* __restrict__ scores)
{
    __shared__ u16 AsH[128 * 64];
    __shared__ u16 AsP[128 * 64];
    __shared__ u16 BsH[128 * 64];
    __shared__ u16 BsP[128 * 64];
    __shared__ float qs[4 * 512];     // up to 4 distinct q rows per block
    __shared__ float qbs[4 * 128];    // qw + b1 per (b, col)
    __shared__ float w2s[128];
    __shared__ int   hids[128];
    __shared__ int   bmap[128];
    __shared__ float sred[128 * 2];

    int m0 = blockIdx.x * 128;
    int b0 = m0 / LL;
    int t = threadIdx.x, wave = t >> 6, lane = t & 63;

    // ---- prologue: stage per-block metadata ----
    if (t < 128) {
        int g = m0 + t;
        hids[t] = hist_ids[g];
        bmap[t] = g / LL - b0;
        w2s[t] = w2v[t];
    }
    {
        int idx = t * 8, bi = idx >> 9, k = idx & 511;
        int bb = min(b0 + bi, BB - 1);
        int fid = feedid[bb];
        const float4* qp = (const float4*)&feed_table[(size_t)fid * FDIM + k];
        *(float4*)&qs[idx] = qp[0];
        *(float4*)&qs[idx + 4] = qp[1];
    }
    {
        int idx = t * 2, bi = idx >> 7, col = idx & 127;
        int bb = min(b0 + bi, BB - 1);
        float2 qv = *(const float2*)&qw[bb * 128 + col];
        float2 bv = *(const float2*)&b1[col];
        qbs[idx] = qv.x + bv.x;
        qbs[idx + 1] = qv.y + bv.y;
    }
    __syncthreads();

    f32x4 acc[4][4];
    f32x4 zz = {0.f, 0.f, 0.f, 0.f};
    #pragma unroll
    for (int i = 0; i < 4; i++)
        #pragma unroll
        for (int j = 0; j < 4; j++) acc[i][j] = zz;
    int wm = (wave >> 1) * 64, wn = (wave & 1) * 64;
    int lrow = lane >> 3, lk8 = (lane & 7) * 8;
    int col0 = (t & 7) * 8;

    for (int kt = 0; kt < 512; kt += 64) {
        // B: global_load_lds of Wh / Wp tiles (L2-resident after first pass)
        #pragma unroll
        for (int j = 0; j < 4; ++j) {
            int c = wave * 4 + j;
            int row = c * 8 + lrow;
            load16_lds(WHP_T + (size_t)row * 1024 + kt + lk8, &BsH[c * 512]);
            load16_lds(WHP_T + (size_t)row * 1024 + 512 + kt + lk8, &BsP[c * 512]);
        }
        // A: reg-staged gather + cvt (f32 -> bf16 forces the reg path)
        #pragma unroll
        for (int bt = 0; bt < 4; ++bt) {
            int row = (t >> 3) + bt * 32;
            int hid = hids[row];
            const float4* hp = (const float4*)&feed_table[(size_t)hid * FDIM + kt + col0];
            float4 h0 = hp[0], h1 = hp[1];
            const float* qrow = &qs[bmap[row] * 512 + kt + col0];
            float4 q0 = *(const float4*)qrow;
            float4 q1 = *(const float4*)(qrow + 4);
            ushort8 hv, pv;
            cvt8(h0, h1, hv);
            float4 p0 = make_float4(h0.x*q0.x, h0.y*q0.y, h0.z*q0.z, h0.w*q0.w);
            float4 p1 = make_float4(h1.x*q1.x, h1.y*q1.y, h1.z*q1.z, h1.w*q1.w);
            cvt8(p0, p1, pv);
            *(ushort8*)&AsH[row * 64 + col0] = hv;
            *(ushort8*)&AsP[row * 64 + col0] = pv;
            *(ushort8*)&Ah[(size_t)(m0 + row) * 512 + kt + col0] = hv;  // side-write
        }
        __syncthreads();
        #pragma unroll
        for (int ks = 0; ks < 2; ++ks) {
            int kk = ks * 32 + (lane >> 4) * 8;
            short8 ah[4], ap[4], bh[4], bp[4];
            #pragma unroll
            for (int i = 0; i < 4; i++) {
                ah[i] = *(const short8*)&AsH[(wm + i * 16 + (lane & 15)) * 64 + kk];
                ap[i] = *(const short8*)&AsP[(wm + i * 16 + (lane & 15)) * 64 + kk];
            }
            #pragma unroll
            for (int j = 0; j < 4; j++) {
                bh[j] = *(const short8*)&BsH[(wn + j * 16 + (lane & 15)) * 64 + kk];
                bp[j] = *(const short8*)&BsP[(wn + j * 16 + (lane & 15)) * 64 + kk];
            }
            #pragma unroll
            for (int i = 0; i < 4; i++)
                #pragma unroll
                for (int j = 0; j < 4; j++) {
                    acc[i][j] = __builtin_amdgcn_mfma_f32_16x16x32_bf16(
                        ah[i], bh[j], acc[i][j], 0, 0, 0);
                    acc[i][j] = __builtin_amdgcn_mfma_f32_16x16x32_bf16(
                        ap[i], bp[j], acc[i][j], 0, 0, 0);
                }
        }
        __syncthreads();
    }

    // ---- epilogue: per-row score = sum_col relu(acc + qw + b1) * w2 ----
    float b2 = b2p[0];
    #pragma unroll
    for (int i = 0; i < 4; ++i) {
        #pragma unroll
        for (int r = 0; r < 4; ++r) {
            int rowl = wm + i * 16 + (lane >> 4) * 4 + r;
            int bi = bmap[rowl];
            float s = 0.f;
            #pragma unroll
            for (int j = 0; j < 4; ++j) {
                int col = wn + j * 16 + (lane & 15);
                float v = acc[i][j][r] + qbs[bi * 128 + col];
                s += fmaxf(v, 0.f) * w2s[col];
            }
            s += __shfl_xor(s, 1, 64);
            s += __shfl_xor(s, 2, 64);
            s += __shfl_xor(s, 4, 64);
            s += __shfl_xor(s, 8, 64);
            if ((lane & 15) == 0) sred[rowl * 2 + (wave & 1)] = s;
        }
    }
    __syncthreads();
    if (t < 128) scores[m0 + t] = sred[t * 2] + sred[t * 2 + 1] + b2;
}

// ---------- K4: softmax over L + user_interest ----------
__global__ __launch_bounds__(256) void softmax_ui(
    const float* __restrict__ scores, const u16* __restrict__ Ah,
    u16* __restrict__ dnn_in)
{
    int b = blockIdx.x, t = threadIdx.x;
    int wave = t >> 6, lane = t & 63;
    __shared__ float sc[52];
    if (wave == 0) {
        float x = (lane < LL) ? scores[b * LL + lane] : -1e30f;
        float mx = wave_max(x);
        float e = (lane < LL) ? __expf(x - mx) : 0.f;
        float s = wave_sum(e);
        if (lane < LL) sc[lane] = e / s;
    }
    __syncthreads();
    int d = t * 2;
    float a0 = 0.f, a1 = 0.f;
    const u16* base = Ah + (size_t)b * LL * 512 + d;
    for (int l = 0; l < LL; ++l) {
        u32 v = *(const u32*)(base + (size_t)l * 512);
        float al = sc[l];
        a0 += al * bf2f((u16)(v & 0xffff));
        a1 += al * bf2f((u16)(v >> 16));
    }
    dnn_in[(size_t)b * KDNN + 648 + d] = f2bf(a0);
    dnn_in[(size_t)b * KDNN + 648 + d + 1] = f2bf(a1);
}

// ---------- K5: MMOE + task heads ----------
__global__ __launch_bounds__(256) void mmoe_head(
    const float* __restrict__ dnn_out, const float* __restrict__ expert_w,
    const float* __restrict__ gate_w, const float* __restrict__ out_w,
    const float* __restrict__ out_b, float* __restrict__ out)
{
    int wave = threadIdx.x >> 6, lane = threadIdx.x & 63;
    int b = blockIdx.x * 4 + wave;
    __shared__ float ds[4][128];
    __shared__ float eo[4][64];
    __shared__ float gt[4][32];
    ds[wave][lane] = dnn_out[b * 128 + lane];
    ds[wave][lane + 64] = dnn_out[b * 128 + 64 + lane];
    __syncthreads();
    int e = lane >> 3, o = lane & 7;
    float acc = 0.f;
    for (int k = 0; k < 128; ++k)
        acc += ds[wave][k] * expert_w[(e * 128 + k) * 8 + o];
    eo[wave][lane] = acc;
    if (lane < 32) {
        int tt = lane >> 3, ee = lane & 7;
        float g = 0.f;
        for (int k = 0; k < 128; ++k)
            g += ds[wave][k] * gate_w[(tt * 128 + k) * 8 + ee];
        float m = g;
        #pragma unroll
        for (int off = 4; off; off >>= 1) m = fmaxf(m, __shfl_xor(m, off, 8));
        float ex = __expf(g - m);
        float s = ex;
        #pragma unroll
        for (int off = 4; off; off >>= 1) s += __shfl_xor(s, off, 8);
        gt[wave][lane] = ex / s;
    }
    __syncthreads();
    if (lane < 32) {
        int tt = lane >> 3, o2 = lane & 7;
        float to = 0.f;
        #pragma unroll
        for (int ee = 0; ee < 8; ++ee)
            to += gt[wave][tt * 8 + ee] * eo[wave][ee * 8 + o2];
        float pl = to * out_w[tt * 8 + o2];
        #pragma unroll
        for (int off = 4; off; off >>= 1) pl += __shfl_xor(pl, off, 8);
        if (o2 == 0) {
            float logit = pl + out_b[tt];
            out[b * 4 + tt] = 1.f / (1.f + __expf(-logit));
        }
    }
}

// ---------- host ----------
extern "C" void kernel_launch(void* const* d_in, const int* in_sizes, int n_in,
                              void* d_out, int out_size, void* d_ws, size_t ws_size,
                              hipStream_t stream)
{
    const int*   sparse_ids = (const int*)d_in[0];
    const float* dense      = (const float*)d_in[1];
    const int*   feedid     = (const int*)d_in[2];
    const int*   hist_ids   = (const int*)d_in[3];
    const float* emb_tables = (const float*)d_in[4];
    const float* feed_table = (const float*)d_in[5];
    const float* attn_w1    = (const float*)d_in[6];
    const float* attn_b1    = (const float*)d_in[7];
    const float* attn_w2    = (const float*)d_in[8];
    const float* attn_b2    = (const float*)d_in[9];
    const float* dnn_w1     = (const float*)d_in[10];
    const float* dnn_b1     = (const float*)d_in[11];
    const float* dnn_w2     = (const float*)d_in[12];
    const float* dnn_b2     = (const float*)d_in[13];
    const float* expert_w   = (const float*)d_in[14];
    const float* gate_w     = (const float*)d_in[15];
    const float* out_w      = (const float*)d_in[16];
    const float* out_b      = (const float*)d_in[17];
    float* out = (float*)d_out;

    char* ws = (char*)d_ws;
    size_t off = 0;
    auto alloc = [&](size_t bytes) {
        char* p = ws + off;
        off += (bytes + 255) & ~(size_t)255;
        return p;
    };
    u16* WHP_T = (u16*)alloc(131072 * 2);
    u16* WQ_T  = (u16*)alloc(65536 * 2);
    u16* W1D_T = (u16*)alloc((size_t)HID1 * KDNN * 2);
    u16* W2D_T = (u16*)alloc((size_t)HID2 * HID1 * 2);
    u16* AQ    = (u16*)alloc((size_t)BB * FDIM * 2);
    float* QW  = (float*)alloc((size_t)BB * 128 * 4);
    u16* DNNIN = (u16*)alloc((size_t)BB * KDNN * 2);
    u16* Z     = (u16*)alloc((size_t)BB * HID1 * 2);
    float* DOUT= (float*)alloc((size_t)BB * HID2 * 4);
    float* SCORES = (float*)alloc((size_t)ROWS * 4);
    u16* Ah    = (u16*)alloc((size_t)ROWS * 512 * 2);

    prep_weights<<<2112, 256, 0, stream>>>(attn_w1, dnn_w1, dnn_w2,
                                           WHP_T, WQ_T, W1D_T, W2D_T);
    gather_b<<<BB, 256, 0, stream>>>(sparse_ids, dense, feedid, emb_tables,
                                     feed_table, DNNIN, AQ);
    gemm_bt<false, false><<<dim3(BB / 128, 1), 256, 0, stream>>>(
        AQ, 512, WQ_T, 512, nullptr, QW, BB, 128, 512);
    din_gemm<<<ROWS / 128, 256, 0, stream>>>(
        hist_ids, feedid, feed_table, WHP_T, QW, attn_b1, attn_w2, attn_b2,
        Ah, SCORES);
    softmax_ui<<<BB, 256, 0, stream>>>(SCORES, Ah, DNNIN);
    gemm_bt<true, true><<<dim3(BB / 128, HID1 / 128), 256, 0, stream>>>(
        DNNIN, KDNN, W1D_T, KDNN, dnn_b1, Z, BB, HID1, KDNN);
    gemm_bt<true, false><<<dim3(BB / 128, 1), 256, 0, stream>>>(
        Z, HID1, W2D_T, HID1, dnn_b2, DOUT, BB, HID2, HID1);
    mmoe_head<<<BB / 4, 256, 0, stream>>>(DOUT, expert_w, gate_w, out_w,
                                          out_b, out);
}